// Round 11
// baseline (1780.529 us; speedup 1.0000x reference)
//
#include <hip/hip_runtime.h>
#include <stdint.h>

#define NN 100000   // nodes
#define NE 400000   // real edges (self loops excluded from streams)
#define NT 500000   // NE + NN (full alpha table size)
#define DA 98       // atom feature dim
#define DB 13       // bond feature dim
#define EMB 128
#define HE 512      // HEADS * EMB
#define NWAVE 8192  // 2048 blocks x 4 waves

typedef unsigned short ushort_t;
typedef __bf16 bf16x8 __attribute__((ext_vector_type(8)));
typedef float floatx4 __attribute__((ext_vector_type(4)));
typedef __fp16 fp16v2 __attribute__((ext_vector_type(2)));

__device__ __forceinline__ float prelu_f(float x, float a) { return x >= 0.f ? x : a * x; }

__device__ __forceinline__ ushort_t f2bf(float f) {
    unsigned u = __float_as_uint(f);
    unsigned r = (u + 0x7fffu + ((u >> 16) & 1u)) >> 16;  // RNE
    return (ushort_t)r;
}
__device__ __forceinline__ float bflo(unsigned u) { return __uint_as_float(u << 16); }
__device__ __forceinline__ float bfhi(unsigned u) { return __uint_as_float(u & 0xffff0000u); }

// 2 f16 MACs + f32 accumulate in one VALU op (v_dot2_f32_f16)
__device__ __forceinline__ float dot2(unsigned a, unsigned b, float c) {
    return __builtin_amdgcn_fdot2(__builtin_bit_cast(fp16v2, a), __builtin_bit_cast(fp16v2, b), c, false);
}

__device__ __forceinline__ unsigned pk2(float lo, float hi) {
    fp16v2 p = __builtin_amdgcn_cvt_pkrtz(lo, hi);
    return __builtin_bit_cast(unsigned, p);
}

// ----------------- CSR build (edge_index is int32) -----------------
// counts INCLUDE self loops (full CSR offsets used for the alpha layout)
__global__ void k_count(const int* __restrict__ ei, int* __restrict__ sc, int* __restrict__ dc) {
    int e = blockIdx.x * 256 + threadIdx.x;
    if (e >= NT) return;
    int s, d;
    if (e < NE) { s = ei[e]; d = ei[NE + e]; } else { s = d = e - NE; }
    atomicAdd(sc + s, 1);
    atomicAdd(dc + d, 1);
}

__global__ void k_scan1(const int* __restrict__ cnt, int* __restrict__ part, int* __restrict__ bsum) {
    __shared__ int tmp[512];
    int t = threadIdx.x, i = blockIdx.x * 512 + t;
    int v = (i < NN) ? cnt[i] : 0;
    tmp[t] = v;
    __syncthreads();
    for (int off = 1; off < 512; off <<= 1) {
        int x = (t >= off) ? tmp[t - off] : 0;
        __syncthreads();
        tmp[t] += x;
        __syncthreads();
    }
    if (i < NN) part[i] = tmp[t] - v;
    if (t == 511) bsum[blockIdx.x] = tmp[t];
}

__global__ void k_scan2(int* __restrict__ bsum, int nb) {
    __shared__ int tmp[256];
    int t = threadIdx.x;
    int v = (t < nb) ? bsum[t] : 0;
    tmp[t] = v;
    __syncthreads();
    for (int off = 1; off < 256; off <<= 1) {
        int x = (t >= off) ? tmp[t - off] : 0;
        __syncthreads();
        tmp[t] += x;
        __syncthreads();
    }
    if (t < nb) bsum[t] = tmp[t] - v;
}

// cur[i] = off - i  (compact cursor base: real-edge stream excludes self loops)
__global__ void k_scan3(const int* __restrict__ part, const int* __restrict__ bsum,
                        int* __restrict__ off, int* __restrict__ cur) {
    int i = blockIdx.x * 256 + threadIdx.x;
    if (i < NN) {
        int v = part[i] + bsum[i >> 9];
        off[i] = v;
        cur[i] = v - i;
    }
    if (i == 0) off[NN] = NT;
}

// fill compact (real-edge) streams; alpha layout: node n's self edge pinned at
// full position soff[n], real src edges at soff[n]+1+cursor -> s2p_full = cs+s+1
__global__ void k_fill(const int* __restrict__ ei, int* __restrict__ scur2, int* __restrict__ dcur2,
                       int* __restrict__ seid2, int* __restrict__ deid2, int* __restrict__ s2p_full) {
    int e = blockIdx.x * 256 + threadIdx.x;
    if (e >= NE) return;
    int s = ei[e], d = ei[NE + e];
    int cs = atomicAdd(scur2 + s, 1);
    seid2[cs] = e;
    s2p_full[e] = cs + s + 1;
    deid2[atomicAdd(dcur2 + d, 1)] = e;
}

// per-wave node ranges over COMPACT offsets (doff[n]-n, soff[n]-n; total NE)
__global__ void k_wrange2(const int* __restrict__ doff, const int* __restrict__ soff,
                          int* __restrict__ nstart, int* __restrict__ nstart_s) {
    int w = blockIdx.x * 256 + threadIdx.x;
    if (w > NWAVE) return;
    long long target = (long long)w * NE / NWAVE;
    int lo = 0, hi = NN;
    while (lo < hi) {
        int mid = (lo + hi) >> 1;
        if ((long long)(doff[mid] - mid) < target) lo = mid + 1; else hi = mid;
    }
    nstart[w] = lo;
    lo = 0; hi = NN;
    while (lo < hi) {
        int mid = (lo + hi) >> 1;
        if ((long long)(soff[mid] - mid) < target) lo = mid + 1; else hi = mid;
    }
    nstart_s[w] = lo;
}

// dst-order compact tables (sentinel-padded to NE+4): {src, full alpha pos} + attrs
__global__ void k_dprep(const int* __restrict__ deid2, const int* __restrict__ ei,
                        const float* __restrict__ ea, const int* __restrict__ s2p_full,
                        int2* __restrict__ sd_d, unsigned* __restrict__ ea_d) {
    int i = blockIdx.x * 256 + threadIdx.x;
    if (i >= NE + 4) return;
    unsigned p[8] = {0, 0, 0, 0, 0, 0, 0, 0};
    int s = 0, pos = 0;
    if (i < NE) {
        int eid = deid2[i];
        s = ei[eid];
        pos = s2p_full[eid];
        float v[DB];
        #pragma unroll
        for (int k = 0; k < DB; ++k) v[k] = ea[(size_t)eid * DB + k];
        #pragma unroll
        for (int kp = 0; kp < 6; ++kp) p[kp] = pk2(v[2 * kp], v[2 * kp + 1]);
        p[6] = pk2(v[12], 0.f);
    }
    uint4* o = (uint4*)&ea_d[(size_t)i * 8];
    o[0] = make_uint4(p[0], p[1], p[2], p[3]);
    o[1] = make_uint4(p[4], p[5], p[6], p[7]);
    sd_d[i] = make_int2(s, pos);
}

// src-order compact tables (sentinel-padded): dst node + attrs
__global__ void k_sprep(const int* __restrict__ seid2, const int* __restrict__ ei,
                        const float* __restrict__ ea,
                        int* __restrict__ dst_s, unsigned* __restrict__ ea_s) {
    int i = blockIdx.x * 256 + threadIdx.x;
    if (i >= NE + 4) return;
    unsigned p[8] = {0, 0, 0, 0, 0, 0, 0, 0};
    int d = 0;
    if (i < NE) {
        int eid = seid2[i];
        d = ei[NE + eid];
        float v[DB];
        #pragma unroll
        for (int k = 0; k < DB; ++k) v[k] = ea[(size_t)eid * DB + k];
        #pragma unroll
        for (int kp = 0; kp < 6; ++kp) p[kp] = pk2(v[2 * kp], v[2 * kp + 1]);
        p[6] = pk2(v[12], 0.f);
    }
    uint4* o = (uint4*)&ea_s[(size_t)i * 8];
    o[0] = make_uint4(p[0], p[1], p[2], p[3]);
    o[1] = make_uint4(p[4], p[5], p[6], p[7]);
    dst_s[i] = d;
}

// ----------------- fused weight/input prep (4 kernels in one) ----------------
__global__ void k_prep_all(const float* __restrict__ x, const float* __restrict__ xembW,
                           const float* __restrict__ wlW, const float* __restrict__ eeW,
                           ushort_t* __restrict__ xb, ushort_t* __restrict__ Wxt,
                           ushort_t* __restrict__ Wtg, unsigned* __restrict__ eeWp) {
    int idx = blockIdx.x * 256 + threadIdx.x;
    if (idx < NN * 128) {
        int col = idx & 127, n = idx >> 7;
        float v = (col < DA) ? x[(size_t)n * DA + col] : 0.f;
        xb[idx] = f2bf(v);
        return;
    }
    idx -= NN * 128;
    if (idx < 128 * 128) {
        int k = idx & 127, n = idx >> 7;
        float v = (k < DA) ? xembW[(size_t)k * EMB + n] : 0.f;
        Wxt[idx] = f2bf(v);
        return;
    }
    idx -= 128 * 128;
    if (idx < 4 * 512 * 128) {
        int k = idx & 127;
        int n = (idx >> 7) & 511;
        int l = idx >> 16;
        Wtg[idx] = f2bf(wlW[(size_t)l * 65536 + k * 512 + n]);
        return;
    }
    idx -= 4 * 512 * 128;
    if (idx < 4 * 7 * 512) {
        int l = idx / 3584;
        int rem = idx - l * 3584;
        int kp = rem >> 9;
        int ch = rem & 511;
        float lo = eeW[((size_t)l * DB + 2 * kp) * HE + ch];
        float hi = (2 * kp + 1 < DB) ? eeW[((size_t)l * DB + 2 * kp + 1) * HE + ch] : 0.f;
        eeWp[idx] = pk2(lo, hi);
    }
}
#define PREP_TOTAL (NN * 128 + 128 * 128 + 4 * 512 * 128 + 4 * 7 * 512)

// ----------------- input embedding via MFMA: h = prelu(x @ x_emb_W) ----------
__global__ __launch_bounds__(256) void k_embed_m(const ushort_t* __restrict__ xb, const ushort_t* __restrict__ Wxt,
                                                 const float* __restrict__ pg, ushort_t* __restrict__ hb) {
    __shared__ ushort_t At[64 * 136];    // 17.4 KB
    __shared__ ushort_t Bt[128 * 136];   // 34.8 KB
    int t = threadIdx.x;
    int m0 = blockIdx.x * 64;
    for (int idx = t; idx < 64 * 16; idx += 256) {
        int r = idx >> 4, co = (idx & 15) * 8;
        int gr = m0 + r; if (gr >= NN) gr = 0;
        *(uint4*)&At[r * 136 + co] = *(const uint4*)&xb[(size_t)gr * 128 + co];
    }
    for (int idx = t; idx < 128 * 16; idx += 256) {
        int n = idx >> 4, ko = (idx & 15) * 8;
        *(uint4*)&Bt[n * 136 + ko] = *(const uint4*)&Wxt[n * 128 + ko];
    }
    float p = pg[0];
    __syncthreads();

    int wv = t >> 6, lane = t & 63;
    int ml = lane & 15, kq = lane >> 4;
    int n0w = wv * 32;
    floatx4 acc[4][2];
    #pragma unroll
    for (int mt = 0; mt < 4; ++mt)
        #pragma unroll
        for (int nt = 0; nt < 2; ++nt)
            acc[mt][nt] = (floatx4){0.f, 0.f, 0.f, 0.f};

    #pragma unroll
    for (int k0 = 0; k0 < 128; k0 += 32) {
        bf16x8 af[4], bfv[2];
        #pragma unroll
        for (int mt = 0; mt < 4; ++mt) {
            uint4 u = *(const uint4*)&At[(mt * 16 + ml) * 136 + k0 + kq * 8];
            af[mt] = __builtin_bit_cast(bf16x8, u);
        }
        #pragma unroll
        for (int nt = 0; nt < 2; ++nt) {
            uint4 u = *(const uint4*)&Bt[(n0w + nt * 16 + ml) * 136 + k0 + kq * 8];
            bfv[nt] = __builtin_bit_cast(bf16x8, u);
        }
        #pragma unroll
        for (int mt = 0; mt < 4; ++mt)
            #pragma unroll
            for (int nt = 0; nt < 2; ++nt)
                acc[mt][nt] = __builtin_amdgcn_mfma_f32_16x16x32_bf16(af[mt], bfv[nt], acc[mt][nt], 0, 0, 0);
    }
    #pragma unroll
    for (int nt = 0; nt < 2; ++nt) {
        int col = n0w + nt * 16 + ml;
        #pragma unroll
        for (int mt = 0; mt < 4; ++mt) {
            int row = m0 + mt * 16 + kq * 4;
            #pragma unroll
            for (int q = 0; q < 4; ++q) {
                int r = row + q;
                if (r < NN) hb[(size_t)r * EMB + col] = f2bf(prelu_f(acc[mt][nt][q], p));
            }
        }
    }
}

// ----------------- per-layer GEMM via MFMA + fused attention dots ------------
__global__ __launch_bounds__(256) void k_gemm(const ushort_t* __restrict__ hb, const ushort_t* __restrict__ Wtg,
                                              const float* __restrict__ bl, const float* __restrict__ pa,
                                              const float* __restrict__ attl,
                                              ushort_t* __restrict__ xw,
                                              float* __restrict__ ddst, float* __restrict__ dsrc) {
    __shared__ ushort_t At[64 * 136];    // 17.4 KB (reused as 2 KB reduction scratch)
    __shared__ ushort_t Bt[128 * 136];   // 34.8 KB
    int t = threadIdx.x;
    int m0 = blockIdx.x * 64;
    int h = blockIdx.y;
    int n0 = h * 128;
    for (int idx = t; idx < 64 * 16; idx += 256) {
        int r = idx >> 4, co = (idx & 15) * 8;
        int gr = m0 + r; if (gr >= NN) gr = 0;
        *(uint4*)&At[r * 136 + co] = *(const uint4*)&hb[(size_t)gr * EMB + co];
    }
    for (int idx = t; idx < 128 * 16; idx += 256) {
        int n = idx >> 4, ko = (idx & 15) * 8;
        *(uint4*)&Bt[n * 136 + ko] = *(const uint4*)&Wtg[(size_t)(n0 + n) * 128 + ko];
    }
    float a = pa[0];
    __syncthreads();

    int wv = t >> 6, lane = t & 63;
    int ml = lane & 15, kq = lane >> 4;
    int n0w = wv * 32;
    floatx4 acc[4][2];
    #pragma unroll
    for (int mt = 0; mt < 4; ++mt)
        #pragma unroll
        for (int nt = 0; nt < 2; ++nt)
            acc[mt][nt] = (floatx4){0.f, 0.f, 0.f, 0.f};

    #pragma unroll
    for (int k0 = 0; k0 < 128; k0 += 32) {
        bf16x8 af[4], bfv[2];
        #pragma unroll
        for (int mt = 0; mt < 4; ++mt) {
            uint4 u = *(const uint4*)&At[(mt * 16 + ml) * 136 + k0 + kq * 8];
            af[mt] = __builtin_bit_cast(bf16x8, u);
        }
        #pragma unroll
        for (int nt = 0; nt < 2; ++nt) {
            uint4 u = *(const uint4*)&Bt[(n0w + nt * 16 + ml) * 136 + k0 + kq * 8];
            bfv[nt] = __builtin_bit_cast(bf16x8, u);
        }
        #pragma unroll
        for (int mt = 0; mt < 4; ++mt)
            #pragma unroll
            for (int nt = 0; nt < 2; ++nt)
                acc[mt][nt] = __builtin_amdgcn_mfma_f32_16x16x32_bf16(af[mt], bfv[nt], acc[mt][nt], 0, 0, 0);
    }
    __syncthreads();   // At/Bt now dead — safe to reuse At as scratch
    float* sdd = (float*)At;          // [4 waves][64 rows]
    float* sds = (float*)At + 256;

    float pd[4][4], ps[4][4];
    #pragma unroll
    for (int mt = 0; mt < 4; ++mt)
        #pragma unroll
        for (int q = 0; q < 4; ++q) { pd[mt][q] = 0.f; ps[mt][q] = 0.f; }

    #pragma unroll
    for (int nt = 0; nt < 2; ++nt) {
        int ch = n0w + nt * 16 + ml;        // channel within head, 0..127
        int col = n0 + ch;
        float bv = bl[col];
        float a1v = attl[h * 256 + ch];
        float a2v = attl[h * 256 + 128 + ch];
        #pragma unroll
        for (int mt = 0; mt < 4; ++mt) {
            int row = m0 + mt * 16 + kq * 4;
            #pragma unroll
            for (int q = 0; q < 4; ++q) {
                int r = row + q;
                float v = prelu_f(acc[mt][nt][q] + bv, a);
                if (r < NN) xw[(size_t)r * HE + col] = f2bf(v);
                pd[mt][q] += v * a1v;
                ps[mt][q] += v * a2v;
            }
        }
    }
    #pragma unroll
    for (int mt = 0; mt < 4; ++mt)
        #pragma unroll
        for (int q = 0; q < 4; ++q) {
            float d = pd[mt][q], s = ps[mt][q];
            #pragma unroll
            for (int m = 1; m < 16; m <<= 1) {
                d += __shfl_xor(d, m, 64);
                s += __shfl_xor(s, m, 64);
            }
            if (ml == 0) {
                int lr = mt * 16 + kq * 4 + q;
                sdd[wv * 64 + lr] = d;
                sds[wv * 64 + lr] = s;
            }
        }
    __syncthreads();
    if (t < 64) {
        int r = m0 + t;
        if (r < NN) {
            float d = sdd[t] + sdd[64 + t] + sdd[128 + t] + sdd[192 + t];
            float s = sds[t] + sds[64 + t] + sds[128 + t] + sds[192 + t];
            ddst[r * 4 + h] = d;
            dsrc[r * 4 + h] = s;
        }
    }
}

// ----------------- fused per-edge logits + segment softmax -------------------
// Compact (real-edge) src-sorted iteration: main loop is branch-free. Self
// logit computed at segment start (closed-form position soff[n]); self-only
// nodes write alpha=1 directly. deg_full<=16 keeps logits in registers
// (slot 0 = self); larger segments fall back to store/drain/reload.
__global__ __launch_bounds__(256) void k_edgesm(const int* __restrict__ nstart_s,
                                                const int* __restrict__ soff,
                                                const unsigned* __restrict__ ea_s,
                                                const int* __restrict__ dst_s,
                                                const unsigned* __restrict__ eeWp, const float* __restrict__ ebl,
                                                const float* __restrict__ attl, const float* __restrict__ pa,
                                                const float* __restrict__ ddst, const float* __restrict__ dsrc,
                                                float* __restrict__ alpha_s) {
    int t = threadIdx.x;
    float a = pa[0];
    int lane = t & 63;
    int w = blockIdx.x * 4 + (t >> 6);
    int hd = lane >> 4;
    int cm = (lane & 15) * 8;
    int c0 = lane * 8;
    uint4 wpa[7], wpb[7];
    #pragma unroll
    for (int kp = 0; kp < 7; ++kp) {
        wpa[kp] = *(const uint4*)&eeWp[kp * HE + c0];
        wpb[kp] = *(const uint4*)&eeWp[kp * HE + c0 + 4];
    }
    float a2[8], eb[8];
    #pragma unroll
    for (int q = 0; q < 8; ++q) {
        a2[q] = attl[hd * 256 + 128 + cm + q];
        eb[q] = ebl[c0 + q];
    }
    // fully-reduced per-head self-loop ee·a2 term
    float pselfR = 0.f;
    #pragma unroll
    for (int q = 0; q < 8; ++q) pselfR += prelu_f(eb[q], a) * a2[q];
    #pragma unroll
    for (int m = 1; m < 16; m <<= 1) pselfR += __shfl_xor(pselfR, m, 64);

    int head = lane & 3;
    int slot = lane >> 2;

    int n0 = nstart_s[w], n1 = nstart_s[w + 1];
    if (n0 >= n1) return;
    int e0 = soff[n0] - n0;
    int e1 = soff[n1] - n1;

    int n = n0;
    int sBase = soff[n0];
    // leading self-only nodes: softmax of one element = 1
    while (n < n1) {
        int nbq = soff[n + 1];
        if (nbq - (n + 1) != e0) break;
        if ((lane & 15) == 0) alpha_s[(size_t)sBase * 4 + hd] = 1.0f;
        sBase = nbq; ++n;
    }
    if (e0 >= e1) return;

    // prologue (sentinel-padded streams)
    uint4 eaAa = *(const uint4*)&ea_s[(size_t)e0 * 8];
    uint4 eaAb = *(const uint4*)&ea_s[(size_t)e0 * 8 + 4];
    int dA = dst_s[e0], dB = dst_s[e0 + 1];
    float diA = ddst[dA * 4 + hd];

    int nb = soff[n + 1];          // full end of current node
    int bEnd = nb - (n + 1);       // compact end
    int b = e0;
    bool small = (nb - sBase) <= 16;
    float sj = dsrc[n * 4 + hd];
    float diSelf = ddst[n * 4 + hd];
    float lgSelf = prelu_f(diSelf + sj + pselfR, a);
    float mx = lgSelf;
    float myLg;
    { float lgSH = __shfl(lgSelf, head * 16, 64); myLg = (slot == 0) ? lgSH : -1e30f; }
    if (!small && (lane & 15) == 0) alpha_s[(size_t)sBase * 4 + hd] = lgSelf;

    for (int i = e0; i < e1; ++i) {
        // prefetch slot i+1 attrs, i+2 dst, i+1 ddst
        uint4 eaNa = *(const uint4*)&ea_s[(size_t)(i + 1) * 8];
        uint4 eaNb = *(const uint4*)&ea_s[(size_t)(i + 1) * 8 + 4];
        int dC = dst_s[i + 2];
        float diB = ddst[dB * 4 + hd];
        // ee dot for slot i (branch-free: all edges are real)
        unsigned ec[7] = {eaAa.x, eaAa.y, eaAa.z, eaAa.w, eaAb.x, eaAb.y, eaAb.z};
        float v[8];
        #pragma unroll
        for (int q = 0; q < 8; ++q) v[q] = eb[q];
        #pragma unroll
        for (int kp = 0; kp < 7; ++kp) {
            v[0] = dot2(ec[kp], wpa[kp].x, v[0]);
            v[1] = dot2(ec[kp], wpa[kp].y, v[1]);
            v[2] = dot2(ec[kp], wpa[kp].z, v[2]);
            v[3] = dot2(ec[kp], wpa[kp].w, v[3]);
            v[4] = dot2(ec[kp], wpb[kp].x, v[4]);
            v[5] = dot2(ec[kp], wpb[kp].y, v[5]);
            v[6] = dot2(ec[kp], wpb[kp].z, v[6]);
            v[7] = dot2(ec[kp], wpb[kp].w, v[7]);
        }
        float p = 0.f;
        #pragma unroll
        for (int q = 0; q < 8; ++q) p += prelu_f(v[q], a) * a2[q];
        #pragma unroll
        for (int m = 1; m < 16; m <<= 1) p += __shfl_xor(p, m, 64);
        float lg = prelu_f(diA + sj + p, a);   // all lanes hold head(hd)'s logit
        if (small) {
            float lgH = __shfl(lg, head * 16, 64);   // my head's logit
            myLg = (slot == (i - b) + 1) ? lgH : myLg;
        } else if ((lane & 15) == 0) {
            alpha_s[(size_t)(sBase + 1 + (i - b)) * 4 + hd] = lg;
            mx = fmaxf(mx, lg);
        }
        // segment end: softmax over full [sBase, nb) incl self
        if (i + 1 == bEnd) {
            int degF = nb - sBase;
            if (small) {
                float mh = myLg;
                #pragma unroll
                for (int m = 4; m < 64; m <<= 1) mh = fmaxf(mh, __shfl_xor(mh, m, 64));
                float ex = __expf(myLg - mh);        // empty slots -> 0
                float s = ex;
                #pragma unroll
                for (int m = 4; m < 64; m <<= 1) s += __shfl_xor(s, m, 64);
                float inv = 1.f / (s + 1e-16f);
                if (slot < degF)
                    alpha_s[(size_t)(sBase + slot) * 4 + head] = ex * inv;
            } else {
                float m0v = __shfl(mx, 0, 64), m1v = __shfl(mx, 16, 64),
                      m2v = __shfl(mx, 32, 64), m3v = __shfl(mx, 48, 64);
                float mh = head == 0 ? m0v : head == 1 ? m1v : head == 2 ? m2v : m3v;
                asm volatile("s_waitcnt vmcnt(0)" ::: "memory");  // logits visible
                float s = 0.f;
                for (int idx = sBase + (lane >> 2); idx < nb; idx += 16) {
                    float x = alpha_s[(size_t)idx * 4 + head];
                    float ex = __expf(x - mh);
                    s += ex;
                    alpha_s[(size_t)idx * 4 + head] = ex;
                }
                #pragma unroll
                for (int m = 4; m < 64; m <<= 1) s += __shfl_xor(s, m, 64);
                float inv = 1.f / (s + 1e-16f);
                asm volatile("s_waitcnt vmcnt(0)" ::: "memory");
                for (int idx = sBase + (lane >> 2); idx < nb; idx += 16)
                    alpha_s[(size_t)idx * 4 + head] *= inv;
            }
            ++n; sBase = nb;
            // following self-only nodes
            while (n < n1) {
                int nbq = soff[n + 1];
                if (nbq - (n + 1) != i + 1) break;
                if ((lane & 15) == 0) alpha_s[(size_t)sBase * 4 + hd] = 1.0f;
                sBase = nbq; ++n;
            }
            if (i + 1 < e1) {
                nb = soff[n + 1];
                bEnd = nb - (n + 1);
                b = i + 1;
                small = (nb - sBase) <= 16;
                sj = dsrc[n * 4 + hd];
                diSelf = ddst[n * 4 + hd];
                lgSelf = prelu_f(diSelf + sj + pselfR, a);
                mx = lgSelf;
                float lgSH = __shfl(lgSelf, head * 16, 64);
                myLg = (slot == 0) ? lgSH : -1e30f;
                if (!small && (lane & 15) == 0) alpha_s[(size_t)sBase * 4 + hd] = lgSelf;
            }
        }
        // rotate
        eaAa = eaNa; eaAb = eaNb;
        dA = dB; dB = dC;
        diA = diB;
    }
}

// ----------------- aggregation + head-mean + bias + LayerNorm (+PReLU) -------
// Compact (real-edge) dst-sorted iteration: main loop branch-free. Self
// contribution (xw[n]+prelu(eb))*alpha[soff[n]] added at node finish, with
// xw[n]/alpha prefetched one node ahead. Empty in-degree nodes handled by
// pre/post while-loops.
__global__ __launch_bounds__(256) void k_aggr(const int* __restrict__ nstart,
                                              const int* __restrict__ doff, const int* __restrict__ soff,
                                              const int2* __restrict__ sd_d,
                                              const unsigned* __restrict__ ea_d,
                                              const unsigned* __restrict__ eeWp, const float* __restrict__ ebl,
                                              const float* __restrict__ pa, const ushort_t* __restrict__ xw,
                                              const float* __restrict__ alpha_s,
                                              const float* __restrict__ gbias, const float* __restrict__ lng,
                                              const float* __restrict__ lnb, const float* __restrict__ pgnn,
                                              int last, ushort_t* __restrict__ hb_out, float* __restrict__ fout) {
    int t = threadIdx.x;
    float a = pa[0], pg = pgnn[0];
    int lane = t & 63;
    int w = blockIdx.x * 4 + (t >> 6);
    int hd = lane >> 4;
    int cm = (lane & 15) * 8;
    int c0 = lane * 8;
    uint4 wpa[7], wpb[7];
    #pragma unroll
    for (int kp = 0; kp < 7; ++kp) {
        wpa[kp] = *(const uint4*)&eeWp[kp * HE + c0];
        wpb[kp] = *(const uint4*)&eeWp[kp * HE + c0 + 4];
    }
    float eb[8], ebp[8];
    #pragma unroll
    for (int q = 0; q < 8; ++q) {
        eb[q] = ebl[c0 + q];
        ebp[q] = prelu_f(eb[q], a);
    }
    float gbv[8], gv[8], bbv[8];
    *(float4*)&gbv[0] = *(const float4*)&gbias[cm];
    *(float4*)&gbv[4] = *(const float4*)&gbias[cm + 4];
    *(float4*)&gv[0]  = *(const float4*)&lng[cm];
    *(float4*)&gv[4]  = *(const float4*)&lng[cm + 4];
    *(float4*)&bbv[0] = *(const float4*)&lnb[cm];
    *(float4*)&bbv[4] = *(const float4*)&lnb[cm + 4];

    // node finish: add self term, head-mean, LN, store
    auto finishNode = [&](int node, const float* accp, uint4 xwS, float alS) {
        float xvS[8] = {bflo(xwS.x), bfhi(xwS.x), bflo(xwS.y), bfhi(xwS.y),
                        bflo(xwS.z), bfhi(xwS.z), bflo(xwS.w), bfhi(xwS.w)};
        float hm[8];
        #pragma unroll
        for (int q = 0; q < 8; ++q) {
            float v = accp[q] + (xvS[q] + ebp[q]) * alS;
            v += __shfl_xor(v, 16, 64);
            v += __shfl_xor(v, 32, 64);
            hm[q] = 0.25f * v + gbv[q];
        }
        float s8 = 0.f, q8 = 0.f;
        #pragma unroll
        for (int q = 0; q < 8; ++q) { s8 += hm[q]; q8 += hm[q] * hm[q]; }
        #pragma unroll
        for (int m = 1; m < 16; m <<= 1) {
            s8 += __shfl_xor(s8, m, 64);
            q8 += __shfl_xor(q8, m, 64);
        }
        float mu = s8 * (1.f / 128.f);
        float var = q8 * (1.f / 128.f) - mu * mu;
        float rstd = rsqrtf(var + 1e-5f);
        if (lane < 16) {
            float o[8];
            #pragma unroll
            for (int q = 0; q < 8; ++q) {
                float vv = (hm[q] - mu) * rstd * gv[q] + bbv[q];
                o[q] = last ? vv : prelu_f(vv, pg);
            }
            if (last) {
                float4* op = (float4*)&fout[(size_t)node * EMB + lane * 8];
                op[0] = make_float4(o[0], o[1], o[2], o[3]);
                op[1] = make_float4(o[4], o[5], o[6], o[7]);
            } else {
                uint4 ob;
                ob.x = (unsigned)f2bf(o[0]) | ((unsigned)f2bf(o[1]) << 16);
                ob.y = (unsigned)f2bf(o[2]) | ((unsigned)f2bf(o[3]) << 16);
                ob.z = (unsigned)f2bf(o[4]) | ((unsigned)f2bf(o[5]) << 16);
                ob.w = (unsigned)f2bf(o[6]) | ((unsigned)f2bf(o[7]) << 16);
                *(uint4*)&hb_out[(size_t)node * EMB + lane * 8] = ob;
            }
        }
    };

    int n0 = nstart[w], n1 = nstart[w + 1];
    if (n0 >= n1) return;
    int e0 = doff[n0] - n0;
    int e1 = doff[n1] - n1;
    int n = n0;
    const float accz[8] = {0.f, 0.f, 0.f, 0.f, 0.f, 0.f, 0.f, 0.f};

    // leading empty (no real in-edges) nodes
    while (n < n1) {
        int db = doff[n + 1];
        if (db - (n + 1) != e0) break;
        int so = soff[n];
        uint4 xwS = *(const uint4*)&xw[(size_t)n * HE + c0];
        float alS = alpha_s[(size_t)so * 4 + hd];
        finishNode(n, accz, xwS, alS);
        ++n;
    }
    if (e0 >= e1) return;

    // pipeline prologue (streams sentinel-padded to NE+4)
    int2 rA = sd_d[e0], rB = sd_d[e0 + 1], rN = sd_d[e0 + 2];
    int sA = rA.x, pA = rA.y;
    int sB = rB.x, pB = rB.y;
    int sN = rN.x, pN = rN.y;
    uint4 xwA = *(const uint4*)&xw[(size_t)sA * HE + c0];
    float alA = alpha_s[(size_t)pA * 4 + hd];
    uint4 xwB = *(const uint4*)&xw[(size_t)sB * HE + c0];
    float alB = alpha_s[(size_t)pB * 4 + hd];
    uint4 eaCa = *(const uint4*)&ea_d[(size_t)e0 * 8];
    uint4 eaCb = *(const uint4*)&ea_d[(size_t)e0 * 8 + 4];
    // current node's self term
    uint4 xwSelfA = *(const uint4*)&xw[(size_t)n * HE + c0];
    float alSelfA = alpha_s[(size_t)soff[n] * 4 + hd];

    int b1 = doff[n + 1] - (n + 1);
    float acc[8] = {0.f, 0.f, 0.f, 0.f, 0.f, 0.f, 0.f, 0.f};

    for (int i = e0; i < e1; ++i) {
        // (1) packed ea stream prefetch for i+1
        uint4 eaNa = *(const uint4*)&ea_d[(size_t)(i + 1) * 8];
        uint4 eaNb = *(const uint4*)&ea_d[(size_t)(i + 1) * 8 + 4];
        // (2) gathers for i+2 (indices loaded last iteration)
        uint4 xwC = *(const uint4*)&xw[(size_t)sN * HE + c0];
        float alC = alpha_s[(size_t)pN * 4 + hd];
        // (3) indices for i+3 (one 8B load)
        int2 rN2 = sd_d[i + 3];
        // (4) compute current edge (slot A): ee via 56 dot2, branch-free
        unsigned ec[7] = {eaCa.x, eaCa.y, eaCa.z, eaCa.w, eaCb.x, eaCb.y, eaCb.z};
        float wv[8];
        #pragma unroll
        for (int q = 0; q < 8; ++q) wv[q] = eb[q];
        #pragma unroll
        for (int kp = 0; kp < 7; ++kp) {
            wv[0] = dot2(ec[kp], wpa[kp].x, wv[0]);
            wv[1] = dot2(ec[kp], wpa[kp].y, wv[1]);
            wv[2] = dot2(ec[kp], wpa[kp].z, wv[2]);
            wv[3] = dot2(ec[kp], wpa[kp].w, wv[3]);
            wv[4] = dot2(ec[kp], wpb[kp].x, wv[4]);
            wv[5] = dot2(ec[kp], wpb[kp].y, wv[5]);
            wv[6] = dot2(ec[kp], wpb[kp].z, wv[6]);
            wv[7] = dot2(ec[kp], wpb[kp].w, wv[7]);
        }
        float xv[8] = {bflo(xwA.x), bfhi(xwA.x), bflo(xwA.y), bfhi(xwA.y),
                       bflo(xwA.z), bfhi(xwA.z), bflo(xwA.w), bfhi(xwA.w)};
        #pragma unroll
        for (int q = 0; q < 8; ++q) acc[q] += (xv[q] + prelu_f(wv[q], a)) * alA;
        // (5) node boundary: finish node n (+ any following empty nodes)
        if (i + 1 == b1) {
            finishNode(n, acc, xwSelfA, alSelfA);
            #pragma unroll
            for (int q = 0; q < 8; ++q) acc[q] = 0.f;
            ++n;
            while (n < n1) {
                int db = doff[n + 1];
                if (db - (n + 1) != i + 1) break;
                int so = soff[n];
                uint4 xwS = *(const uint4*)&xw[(size_t)n * HE + c0];
                float alS = alpha_s[(size_t)so * 4 + hd];
                finishNode(n, accz, xwS, alS);
                ++n;
            }
            if (i + 1 < e1) {
                b1 = doff[n + 1] - (n + 1);
                int so = soff[n];
                xwSelfA = *(const uint4*)&xw[(size_t)n * HE + c0];
                alSelfA = alpha_s[(size_t)so * 4 + hd];
            }
        }
        // (6) rotate pipeline
        xwA = xwB; alA = alB;
        xwB = xwC; alB = alC;
        sN = rN2.x; pN = rN2.y;
        eaCa = eaNa; eaCb = eaNb;
    }
}

extern "C" void kernel_launch(void* const* d_in, const int* in_sizes, int n_in,
                              void* d_out, int out_size, void* d_ws, size_t ws_size,
                              hipStream_t stream) {
    const float* x     = (const float*)d_in[0];
    const int*   ei    = (const int*)d_in[1];      // int32 (JAX x64 disabled)
    const float* ea    = (const float*)d_in[2];
    const float* xembW = (const float*)d_in[3];
    const float* pgnn  = (const float*)d_in[4];
    const float* wlW   = (const float*)d_in[5];
    const float* wlb   = (const float*)d_in[6];
    const float* att   = (const float*)d_in[7];
    const float* gbias = (const float*)d_in[8];
    const float* eeW   = (const float*)d_in[9];
    const float* eeb   = (const float*)d_in[10];
    const float* pgat  = (const float*)d_in[11];
    const float* lng   = (const float*)d_in[12];
    const float* lnb   = (const float*)d_in[13];

    char* w = (char*)d_ws;
    size_t off = 0;
    auto alloc = [&](size_t nbytes) -> char* {
        char* p = w + off;
        off += (nbytes + 255) & ~(size_t)255;
        return p;
    };
    ushort_t* hb    = (ushort_t*)alloc((size_t)NN * EMB * 2);   // 25.6 MB bf16
    ushort_t* xw    = (ushort_t*)alloc((size_t)NN * HE * 2);    // 102.4 MB bf16
    ushort_t* Wtg   = (ushort_t*)alloc((size_t)4 * 512 * 128 * 2);
    ushort_t* Wxt   = (ushort_t*)alloc((size_t)128 * 128 * 2);  // 32 KB embed weights
    unsigned* eeWp  = (unsigned*)alloc((size_t)4 * 7 * 512 * 4);
    float*    ddst  = (float*)alloc((size_t)NN * 4 * 4);
    float*    dsrc  = (float*)alloc((size_t)NN * 4 * 4);
    float*    alpha = (float*)alloc((size_t)NT * 4 * 4);        // 8 MB (full src-sorted)
    unsigned* ea_d  = (unsigned*)alloc((size_t)(NE + 4) * 8 * 4); // 12.8 MB dst-ordered
    unsigned* ea_s  = (unsigned*)alloc((size_t)(NE + 4) * 8 * 4); // 12.8 MB src-ordered
    int2* sd_d    = (int2*)alloc((size_t)(NE + 4) * 8);         // {src, full alpha pos}
    int* cnt2     = (int*)alloc((size_t)2 * NN * 4);            // scnt+dcnt adjacent
    int* scnt     = cnt2;
    int* dcnt     = cnt2 + NN;
    int* soff     = (int*)alloc((size_t)(NN + 1) * 4);
    int* doff     = (int*)alloc((size_t)(NN + 1) * 4);
    int* scur     = (int*)alloc((size_t)NN * 4);
    int* dcur     = (int*)alloc((size_t)NN * 4);
    int* seid2    = (int*)alloc((size_t)NE * 4);
    int* deid2    = (int*)alloc((size_t)NE * 4);
    int* s2p      = (int*)alloc((size_t)NE * 4);                // real edge -> full src pos
    int* dst_s    = (int*)alloc((size_t)(NE + 4) * 4);          // src-ordered dst node
    int* nstart   = (int*)alloc((size_t)(NWAVE + 1) * 4);
    int* nstart_s = (int*)alloc((size_t)(NWAVE + 1) * 4);
    int* part     = (int*)alloc((size_t)NN * 4);
    int* bsum     = (int*)alloc(256 * 4);

    // xb (bf16 padded x, 25.6 MB) aliases xw: dead before layer-0 k_gemm writes xw
    ushort_t* xb = xw;

    hipMemsetAsync(cnt2, 0, (size_t)2 * NN * 4, stream);
    k_count<<<(NT + 255) / 256, 256, 0, stream>>>(ei, scnt, dcnt);
    k_scan1<<<196, 512, 0, stream>>>(scnt, part, bsum);
    k_scan2<<<1, 256, 0, stream>>>(bsum, 196);
    k_scan3<<<391, 256, 0, stream>>>(part, bsum, soff, scur);
    k_scan1<<<196, 512, 0, stream>>>(dcnt, part, bsum);
    k_scan2<<<1, 256, 0, stream>>>(bsum, 196);
    k_scan3<<<391, 256, 0, stream>>>(part, bsum, doff, dcur);
    k_fill<<<(NE + 255) / 256, 256, 0, stream>>>(ei, scur, dcur, seid2, deid2, s2p);
    k_wrange2<<<(NWAVE + 1 + 255) / 256, 256, 0, stream>>>(doff, soff, nstart, nstart_s);
    k_dprep<<<(NE + 4 + 255) / 256, 256, 0, stream>>>(deid2, ei, ea, s2p, sd_d, ea_d);
    k_sprep<<<(NE + 4 + 255) / 256, 256, 0, stream>>>(seid2, ei, ea, dst_s, ea_s);
    k_prep_all<<<(PREP_TOTAL + 255) / 256, 256, 0, stream>>>(x, xembW, wlW, eeW, xb, Wxt, Wtg, eeWp);
    k_embed_m<<<(NN + 63) / 64, 256, 0, stream>>>(xb, Wxt, pgnn, hb);

    for (int l = 0; l < 4; ++l) {
        const float* bl  = wlb + (size_t)l * HE;
        const float* al  = att + (size_t)l * 1024;
        const unsigned* eWl = eeWp + (size_t)l * 7 * HE;
        const float* ebl = eeb + (size_t)l * HE;
        const float* pa  = pgat + l;
        const ushort_t* Wt = Wtg + (size_t)l * 512 * 128;
        k_gemm<<<dim3((NN + 63) / 64, 4), 256, 0, stream>>>(hb, Wt, bl, pa, al, xw, ddst, dsrc);
        k_edgesm<<<2048, 256, 0, stream>>>(nstart_s, soff, ea_s, dst_s, eWl, ebl, al, pa,
                                           ddst, dsrc, alpha);
        k_aggr<<<2048, 256, 0, stream>>>(nstart, doff, soff, sd_d, ea_d, eWl, ebl, pa, xw, alpha,
                                         gbias + (size_t)l * EMB, lng + (size_t)l * EMB,
                                         lnb + (size_t)l * EMB, pgnn, (l == 3) ? 1 : 0,
                                         hb, (float*)d_out);
    }
}

// Round 12
// 1738.602 us; speedup vs baseline: 1.0241x; 1.0241x over previous
//
#include <hip/hip_runtime.h>
#include <stdint.h>

#define NN 100000   // nodes
#define NE 400000   // edges before self loops
#define NT 500000   // NE + NN
#define DA 98       // atom feature dim
#define DB 13       // bond feature dim
#define EMB 128
#define HE 512      // HEADS * EMB
#define NWAVE 8192  // 2048 blocks x 4 waves
#define IMSK 0x0FFFFFFF

typedef unsigned short ushort_t;
typedef __bf16 bf16x8 __attribute__((ext_vector_type(8)));
typedef float floatx4 __attribute__((ext_vector_type(4)));
typedef __fp16 fp16v2 __attribute__((ext_vector_type(2)));

__device__ __forceinline__ float prelu_f(float x, float a) { return x >= 0.f ? x : a * x; }

__device__ __forceinline__ ushort_t f2bf(float f) {
    unsigned u = __float_as_uint(f);
    unsigned r = (u + 0x7fffu + ((u >> 16) & 1u)) >> 16;  // RNE
    return (ushort_t)r;
}
__device__ __forceinline__ float bflo(unsigned u) { return __uint_as_float(u << 16); }
__device__ __forceinline__ float bfhi(unsigned u) { return __uint_as_float(u & 0xffff0000u); }

// 2 f16 MACs + f32 accumulate in one VALU op (v_dot2_f32_f16)
__device__ __forceinline__ float dot2(unsigned a, unsigned b, float c) {
    return __builtin_amdgcn_fdot2(__builtin_bit_cast(fp16v2, a), __builtin_bit_cast(fp16v2, b), c, false);
}

__device__ __forceinline__ unsigned pk2(float lo, float hi) {
    fp16v2 p = __builtin_amdgcn_cvt_pkrtz(lo, hi);
    return __builtin_bit_cast(unsigned, p);
}

// ----------------- CSR build (edge_index is int32) -----------------
__global__ void k_count(const int* __restrict__ ei, int* __restrict__ sc, int* __restrict__ dc) {
    int e = blockIdx.x * 256 + threadIdx.x;
    if (e >= NT) return;
    int s, d;
    if (e < NE) { s = ei[e]; d = ei[NE + e]; } else { s = d = e - NE; }
    atomicAdd(sc + s, 1);
    atomicAdd(dc + d, 1);
}

// joint scan over cnt2[2*NN] (scnt | dcnt adjacent). Since sum(scnt)=NT exactly,
// doff[j] = prefix(j+NN) - NT.
__global__ void k_scan1(const int* __restrict__ cnt, int* __restrict__ part, int* __restrict__ bsum) {
    __shared__ int tmp[512];
    int t = threadIdx.x, i = blockIdx.x * 512 + t;
    int v = (i < 2 * NN) ? cnt[i] : 0;
    tmp[t] = v;
    __syncthreads();
    for (int off = 1; off < 512; off <<= 1) {
        int x = (t >= off) ? tmp[t - off] : 0;
        __syncthreads();
        tmp[t] += x;
        __syncthreads();
    }
    if (i < 2 * NN) part[i] = tmp[t] - v;
    if (t == 511) bsum[blockIdx.x] = tmp[t];
}

__global__ void k_scan2(int* __restrict__ bsum, int nb) {
    __shared__ int tmp[512];
    int t = threadIdx.x;
    int v = (t < nb) ? bsum[t] : 0;
    tmp[t] = v;
    __syncthreads();
    for (int off = 1; off < 512; off <<= 1) {
        int x = (t >= off) ? tmp[t - off] : 0;
        __syncthreads();
        tmp[t] += x;
        __syncthreads();
    }
    if (t < nb) bsum[t] = tmp[t] - v;
}

__global__ void k_scan3(const int* __restrict__ part, const int* __restrict__ bsum,
                        int* __restrict__ soff, int* __restrict__ scur,
                        int* __restrict__ doff, int* __restrict__ dcur) {
    int i = blockIdx.x * 256 + threadIdx.x;
    if (i < NN) {
        int v = part[i] + bsum[i >> 9];
        soff[i] = v;
        scur[i] = v;
    } else if (i < 2 * NN) {
        int j = i - NN;
        int v = part[i] + bsum[i >> 9] - NT;
        doff[j] = v;
        dcur[j] = v;
    }
    if (i == 0) { soff[NN] = NT; doff[NN] = NT; }
}

// fill CSR edge lists; also emit s2p (inverse perm) inline — position known here
__global__ void k_fill(const int* __restrict__ ei, int* __restrict__ scur, int* __restrict__ dcur,
                       int* __restrict__ seid, int* __restrict__ deid, int* __restrict__ s2p) {
    int e = blockIdx.x * 256 + threadIdx.x;
    if (e >= NT) return;
    int s, d;
    if (e < NE) { s = ei[e]; d = ei[NE + e]; } else { s = d = e - NE; }
    int p = atomicAdd(scur + s, 1);
    seid[p] = e;
    s2p[e] = p;
    deid[atomicAdd(dcur + d, 1)] = e;
}

// per-wave node ranges for both orders in one launch
__global__ void k_wrange2(const int* __restrict__ doff, const int* __restrict__ soff,
                          int* __restrict__ nstart, int* __restrict__ nstart_s) {
    int w = blockIdx.x * 256 + threadIdx.x;
    if (w > NWAVE) return;
    long long target = (long long)w * NT / NWAVE;
    int lo = 0, hi = NN;
    while (lo < hi) {
        int mid = (lo + hi) >> 1;
        if ((long long)doff[mid] < target) lo = mid + 1; else hi = mid;
    }
    nstart[w] = lo;
    lo = 0; hi = NN;
    while (lo < hi) {
        int mid = (lo + hi) >> 1;
        if ((long long)soff[mid] < target) lo = mid + 1; else hi = mid;
    }
    nstart_s[w] = lo;
}

// dst-order edge tables (sentinel-padded to NT+4): packed {src|flag, src-pos}
// int2 + packed f16 attrs. Self-loop attrs are 0, which exactly matches the
// reference (prelu(0@W+b)=prelu(b)).
__global__ void k_dprep(const int* __restrict__ deid, const int* __restrict__ ei,
                        const float* __restrict__ ea, const int* __restrict__ s2p,
                        int2* __restrict__ sd_d, unsigned* __restrict__ ea_d) {
    int i = blockIdx.x * 256 + threadIdx.x;
    if (i >= NT + 4) return;
    unsigned p[8] = {0, 0, 0, 0, 0, 0, 0, 0};
    int s = 0, pos = 0;
    if (i < NT) {
        int eid = deid[i];
        if (eid < NE) {
            s = ei[eid];
            float v[DB];
            #pragma unroll
            for (int k = 0; k < DB; ++k) v[k] = ea[(size_t)eid * DB + k];
            #pragma unroll
            for (int kp = 0; kp < 6; ++kp) p[kp] = pk2(v[2 * kp], v[2 * kp + 1]);
            p[6] = pk2(v[12], 0.f);
        } else {
            s = (eid - NE) | (1 << 30);   // self-loop flag
        }
        pos = s2p[eid];
    }
    uint4* o = (uint4*)&ea_d[(size_t)i * 8];
    o[0] = make_uint4(p[0], p[1], p[2], p[3]);
    o[1] = make_uint4(p[4], p[5], p[6], p[7]);
    sd_d[i] = make_int2(s, pos);
}

// src-order edge tables (sentinel-padded): dst node (bit30 = self flag) + attrs
__global__ void k_sprep(const int* __restrict__ seid, const int* __restrict__ ei,
                        const float* __restrict__ ea,
                        int* __restrict__ dst_s, unsigned* __restrict__ ea_s) {
    int i = blockIdx.x * 256 + threadIdx.x;
    if (i >= NT + 4) return;
    unsigned p[8] = {0, 0, 0, 0, 0, 0, 0, 0};
    int d = 0;
    if (i < NT) {
        int eid = seid[i];
        if (eid < NE) {
            d = ei[NE + eid];
            float v[DB];
            #pragma unroll
            for (int k = 0; k < DB; ++k) v[k] = ea[(size_t)eid * DB + k];
            #pragma unroll
            for (int kp = 0; kp < 6; ++kp) p[kp] = pk2(v[2 * kp], v[2 * kp + 1]);
            p[6] = pk2(v[12], 0.f);
        } else {
            d = (eid - NE) | (1 << 30);
        }
    }
    uint4* o = (uint4*)&ea_s[(size_t)i * 8];
    o[0] = make_uint4(p[0], p[1], p[2], p[3]);
    o[1] = make_uint4(p[4], p[5], p[6], p[7]);
    dst_s[i] = d;
}

// ----------------- fused weight/input prep (4 kernels in one) ----------------
__global__ void k_prep_all(const float* __restrict__ x, const float* __restrict__ xembW,
                           const float* __restrict__ wlW, const float* __restrict__ eeW,
                           ushort_t* __restrict__ xb, ushort_t* __restrict__ Wxt,
                           ushort_t* __restrict__ Wtg, unsigned* __restrict__ eeWp) {
    int idx = blockIdx.x * 256 + threadIdx.x;
    if (idx < NN * 128) {
        int col = idx & 127, n = idx >> 7;
        float v = (col < DA) ? x[(size_t)n * DA + col] : 0.f;
        xb[idx] = f2bf(v);
        return;
    }
    idx -= NN * 128;
    if (idx < 128 * 128) {
        int k = idx & 127, n = idx >> 7;
        float v = (k < DA) ? xembW[(size_t)k * EMB + n] : 0.f;
        Wxt[idx] = f2bf(v);
        return;
    }
    idx -= 128 * 128;
    if (idx < 4 * 512 * 128) {
        int k = idx & 127;
        int n = (idx >> 7) & 511;
        int l = idx >> 16;
        Wtg[idx] = f2bf(wlW[(size_t)l * 65536 + k * 512 + n]);
        return;
    }
    idx -= 4 * 512 * 128;
    if (idx < 4 * 7 * 512) {
        int l = idx / 3584;
        int rem = idx - l * 3584;
        int kp = rem >> 9;
        int ch = rem & 511;
        float lo = eeW[((size_t)l * DB + 2 * kp) * HE + ch];
        float hi = (2 * kp + 1 < DB) ? eeW[((size_t)l * DB + 2 * kp + 1) * HE + ch] : 0.f;
        eeWp[idx] = pk2(lo, hi);
    }
}
#define PREP_TOTAL (NN * 128 + 128 * 128 + 4 * 512 * 128 + 4 * 7 * 512)

// ----------------- input embedding via MFMA: h = prelu(x @ x_emb_W) ----------
__global__ __launch_bounds__(256) void k_embed_m(const ushort_t* __restrict__ xb, const ushort_t* __restrict__ Wxt,
                                                 const float* __restrict__ pg, ushort_t* __restrict__ hb) {
    __shared__ ushort_t At[64 * 136];    // 17.4 KB
    __shared__ ushort_t Bt[128 * 136];   // 34.8 KB
    int t = threadIdx.x;
    int m0 = blockIdx.x * 64;
    for (int idx = t; idx < 64 * 16; idx += 256) {
        int r = idx >> 4, co = (idx & 15) * 8;
        int gr = m0 + r; if (gr >= NN) gr = 0;
        *(uint4*)&At[r * 136 + co] = *(const uint4*)&xb[(size_t)gr * 128 + co];
    }
    for (int idx = t; idx < 128 * 16; idx += 256) {
        int n = idx >> 4, ko = (idx & 15) * 8;
        *(uint4*)&Bt[n * 136 + ko] = *(const uint4*)&Wxt[n * 128 + ko];
    }
    float p = pg[0];
    __syncthreads();

    int wv = t >> 6, lane = t & 63;
    int ml = lane & 15, kq = lane >> 4;
    int n0w = wv * 32;
    floatx4 acc[4][2];
    #pragma unroll
    for (int mt = 0; mt < 4; ++mt)
        #pragma unroll
        for (int nt = 0; nt < 2; ++nt)
            acc[mt][nt] = (floatx4){0.f, 0.f, 0.f, 0.f};

    #pragma unroll
    for (int k0 = 0; k0 < 128; k0 += 32) {
        bf16x8 af[4], bfv[2];
        #pragma unroll
        for (int mt = 0; mt < 4; ++mt) {
            uint4 u = *(const uint4*)&At[(mt * 16 + ml) * 136 + k0 + kq * 8];
            af[mt] = __builtin_bit_cast(bf16x8, u);
        }
        #pragma unroll
        for (int nt = 0; nt < 2; ++nt) {
            uint4 u = *(const uint4*)&Bt[(n0w + nt * 16 + ml) * 136 + k0 + kq * 8];
            bfv[nt] = __builtin_bit_cast(bf16x8, u);
        }
        #pragma unroll
        for (int mt = 0; mt < 4; ++mt)
            #pragma unroll
            for (int nt = 0; nt < 2; ++nt)
                acc[mt][nt] = __builtin_amdgcn_mfma_f32_16x16x32_bf16(af[mt], bfv[nt], acc[mt][nt], 0, 0, 0);
    }
    #pragma unroll
    for (int nt = 0; nt < 2; ++nt) {
        int col = n0w + nt * 16 + ml;
        #pragma unroll
        for (int mt = 0; mt < 4; ++mt) {
            int row = m0 + mt * 16 + kq * 4;
            #pragma unroll
            for (int q = 0; q < 4; ++q) {
                int r = row + q;
                if (r < NN) hb[(size_t)r * EMB + col] = f2bf(prelu_f(acc[mt][nt][q], p));
            }
        }
    }
}

// ----------------- per-layer GEMM via MFMA + fused attention dots ------------
__global__ __launch_bounds__(256) void k_gemm(const ushort_t* __restrict__ hb, const ushort_t* __restrict__ Wtg,
                                              const float* __restrict__ bl, const float* __restrict__ pa,
                                              const float* __restrict__ attl,
                                              ushort_t* __restrict__ xw,
                                              float* __restrict__ ddst, float* __restrict__ dsrc) {
    __shared__ ushort_t At[64 * 136];    // 17.4 KB (reused as 2 KB reduction scratch)
    __shared__ ushort_t Bt[128 * 136];   // 34.8 KB
    int t = threadIdx.x;
    int m0 = blockIdx.x * 64;
    int h = blockIdx.y;
    int n0 = h * 128;
    for (int idx = t; idx < 64 * 16; idx += 256) {
        int r = idx >> 4, co = (idx & 15) * 8;
        int gr = m0 + r; if (gr >= NN) gr = 0;
        *(uint4*)&At[r * 136 + co] = *(const uint4*)&hb[(size_t)gr * EMB + co];
    }
    for (int idx = t; idx < 128 * 16; idx += 256) {
        int n = idx >> 4, ko = (idx & 15) * 8;
        *(uint4*)&Bt[n * 136 + ko] = *(const uint4*)&Wtg[(size_t)(n0 + n) * 128 + ko];
    }
    float a = pa[0];
    __syncthreads();

    int wv = t >> 6, lane = t & 63;
    int ml = lane & 15, kq = lane >> 4;
    int n0w = wv * 32;
    floatx4 acc[4][2];
    #pragma unroll
    for (int mt = 0; mt < 4; ++mt)
        #pragma unroll
        for (int nt = 0; nt < 2; ++nt)
            acc[mt][nt] = (floatx4){0.f, 0.f, 0.f, 0.f};

    #pragma unroll
    for (int k0 = 0; k0 < 128; k0 += 32) {
        bf16x8 af[4], bfv[2];
        #pragma unroll
        for (int mt = 0; mt < 4; ++mt) {
            uint4 u = *(const uint4*)&At[(mt * 16 + ml) * 136 + k0 + kq * 8];
            af[mt] = __builtin_bit_cast(bf16x8, u);
        }
        #pragma unroll
        for (int nt = 0; nt < 2; ++nt) {
            uint4 u = *(const uint4*)&Bt[(n0w + nt * 16 + ml) * 136 + k0 + kq * 8];
            bfv[nt] = __builtin_bit_cast(bf16x8, u);
        }
        #pragma unroll
        for (int mt = 0; mt < 4; ++mt)
            #pragma unroll
            for (int nt = 0; nt < 2; ++nt)
                acc[mt][nt] = __builtin_amdgcn_mfma_f32_16x16x32_bf16(af[mt], bfv[nt], acc[mt][nt], 0, 0, 0);
    }
    __syncthreads();   // At/Bt now dead — safe to reuse At as scratch
    float* sdd = (float*)At;          // [4 waves][64 rows]
    float* sds = (float*)At + 256;

    float pd[4][4], ps[4][4];
    #pragma unroll
    for (int mt = 0; mt < 4; ++mt)
        #pragma unroll
        for (int q = 0; q < 4; ++q) { pd[mt][q] = 0.f; ps[mt][q] = 0.f; }

    #pragma unroll
    for (int nt = 0; nt < 2; ++nt) {
        int ch = n0w + nt * 16 + ml;        // channel within head, 0..127
        int col = n0 + ch;
        float bv = bl[col];
        float a1v = attl[h * 256 + ch];
        float a2v = attl[h * 256 + 128 + ch];
        #pragma unroll
        for (int mt = 0; mt < 4; ++mt) {
            int row = m0 + mt * 16 + kq * 4;
            #pragma unroll
            for (int q = 0; q < 4; ++q) {
                int r = row + q;
                float v = prelu_f(acc[mt][nt][q] + bv, a);
                if (r < NN) xw[(size_t)r * HE + col] = f2bf(v);
                pd[mt][q] += v * a1v;
                ps[mt][q] += v * a2v;
            }
        }
    }
    #pragma unroll
    for (int mt = 0; mt < 4; ++mt)
        #pragma unroll
        for (int q = 0; q < 4; ++q) {
            float d = pd[mt][q], s = ps[mt][q];
            #pragma unroll
            for (int m = 1; m < 16; m <<= 1) {
                d += __shfl_xor(d, m, 64);
                s += __shfl_xor(s, m, 64);
            }
            if (ml == 0) {
                int lr = mt * 16 + kq * 4 + q;
                sdd[wv * 64 + lr] = d;
                sds[wv * 64 + lr] = s;
            }
        }
    __syncthreads();
    if (t < 64) {
        int r = m0 + t;
        if (r < NN) {
            float d = sdd[t] + sdd[64 + t] + sdd[128 + t] + sdd[192 + t];
            float s = sds[t] + sds[64 + t] + sds[128 + t] + sds[192 + t];
            ddst[r * 4 + h] = d;
            dsrc[r * 4 + h] = s;
        }
    }
}

// ----------------- fused per-edge logits + segment softmax -------------------
// Src-sorted iteration. Self-loop edges (flag bit30 of dst_s) skip the 56-dot2
// chain (wave-uniform branch). Segments with deg<=16 keep logits in registers:
// slot=lane>>2, head=lane&3; one shfl broadcast per edge; max/sum via stride-4
// shfl_xor; single coalesced store. deg>16 falls back to store/drain/reload.
__global__ __launch_bounds__(256) void k_edgesm(const int* __restrict__ nstart_s,
                                                const int* __restrict__ soff,
                                                const unsigned* __restrict__ ea_s,
                                                const int* __restrict__ dst_s,
                                                const unsigned* __restrict__ eeWp, const float* __restrict__ ebl,
                                                const float* __restrict__ attl, const float* __restrict__ pa,
                                                const float* __restrict__ ddst, const float* __restrict__ dsrc,
                                                float* __restrict__ alpha_s) {
    int t = threadIdx.x;
    float a = pa[0];
    int lane = t & 63;
    int w = blockIdx.x * 4 + (t >> 6);
    int hd = lane >> 4;
    int cm = (lane & 15) * 8;
    int c0 = lane * 8;
    uint4 wpa[7], wpb[7];
    #pragma unroll
    for (int kp = 0; kp < 7; ++kp) {
        wpa[kp] = *(const uint4*)&eeWp[kp * HE + c0];
        wpb[kp] = *(const uint4*)&eeWp[kp * HE + c0 + 4];
    }
    float a2[8], eb[8];
    #pragma unroll
    for (int q = 0; q < 8; ++q) {
        a2[q] = attl[hd * 256 + 128 + cm + q];
        eb[q] = ebl[c0 + q];
    }
    // fully-reduced self-loop p (same value for every self edge of this head)
    float pselfR = 0.f;
    #pragma unroll
    for (int q = 0; q < 8; ++q) pselfR += prelu_f(eb[q], a) * a2[q];
    #pragma unroll
    for (int m = 1; m < 16; m <<= 1) pselfR += __shfl_xor(pselfR, m, 64);

    int head = lane & 3;
    int slot = lane >> 2;

    int n0 = nstart_s[w], n1 = nstart_s[w + 1];
    if (n0 >= n1) return;
    int e0 = soff[n0], e1 = soff[n1];

    // prologue (sentinel-padded streams)
    uint4 eaAa = *(const uint4*)&ea_s[(size_t)e0 * 8];
    uint4 eaAb = *(const uint4*)&ea_s[(size_t)e0 * 8 + 4];
    int rA = dst_s[e0], rB = dst_s[e0 + 1];
    int dA = rA & IMSK, fA = rA >> 30;
    int dB = rB & IMSK, fB = rB >> 30;
    float diA = ddst[dA * 4 + hd];

    int n = n0;
    int b = e0;
    int bEnd = soff[n0 + 1];
    bool small = (bEnd - b) <= 16;
    float sj = dsrc[n * 4 + hd];
    float mx = -1e30f;
    float myLg = -1e30f;

    for (int i = e0; i < e1; ++i) {
        // prefetch slot i+1 attrs, i+2 dst, i+1 ddst
        uint4 eaNa = *(const uint4*)&ea_s[(size_t)(i + 1) * 8];
        uint4 eaNb = *(const uint4*)&ea_s[(size_t)(i + 1) * 8 + 4];
        int rC = dst_s[i + 2];
        int dC = rC & IMSK, fC = rC >> 30;
        float diB = ddst[dB * 4 + hd];
        // p for slot i: skip ee chain on self-loops (wave-uniform)
        float p;
        if (__builtin_amdgcn_readfirstlane(fA)) {
            p = pselfR;
        } else {
            unsigned ec[7] = {eaAa.x, eaAa.y, eaAa.z, eaAa.w, eaAb.x, eaAb.y, eaAb.z};
            float v[8];
            #pragma unroll
            for (int q = 0; q < 8; ++q) v[q] = eb[q];
            #pragma unroll
            for (int kp = 0; kp < 7; ++kp) {
                v[0] = dot2(ec[kp], wpa[kp].x, v[0]);
                v[1] = dot2(ec[kp], wpa[kp].y, v[1]);
                v[2] = dot2(ec[kp], wpa[kp].z, v[2]);
                v[3] = dot2(ec[kp], wpa[kp].w, v[3]);
                v[4] = dot2(ec[kp], wpb[kp].x, v[4]);
                v[5] = dot2(ec[kp], wpb[kp].y, v[5]);
                v[6] = dot2(ec[kp], wpb[kp].z, v[6]);
                v[7] = dot2(ec[kp], wpb[kp].w, v[7]);
            }
            p = 0.f;
            #pragma unroll
            for (int q = 0; q < 8; ++q) p += prelu_f(v[q], a) * a2[q];
            #pragma unroll
            for (int m = 1; m < 16; m <<= 1) p += __shfl_xor(p, m, 64);
        }
        float lg = prelu_f(diA + sj + p, a);   // all lanes hold head(hd)'s logit
        if (small) {
            float lgH = __shfl(lg, head * 16, 64);   // logit of my head
            myLg = (slot == (i - b)) ? lgH : myLg;
        } else {
            if ((lane & 15) == 0) {
                alpha_s[(size_t)i * 4 + hd] = lg;
                mx = fmaxf(mx, lg);
            }
        }
        // segment end: softmax over [b, bEnd)
        if (i + 1 == bEnd) {
            if (small) {
                float mh = myLg;
                #pragma unroll
                for (int m = 4; m < 64; m <<= 1) mh = fmaxf(mh, __shfl_xor(mh, m, 64));
                float ex = __expf(myLg - mh);        // empty slots -> 0
                float s = ex;
                #pragma unroll
                for (int m = 4; m < 64; m <<= 1) s += __shfl_xor(s, m, 64);
                float inv = 1.f / (s + 1e-16f);
                if (slot < bEnd - b)
                    alpha_s[(size_t)(b + slot) * 4 + head] = ex * inv;
            } else {
                float m0v = __shfl(mx, 0, 64), m1v = __shfl(mx, 16, 64),
                      m2v = __shfl(mx, 32, 64), m3v = __shfl(mx, 48, 64);
                float mh = head == 0 ? m0v : head == 1 ? m1v : head == 2 ? m2v : m3v;
                asm volatile("s_waitcnt vmcnt(0)" ::: "memory");  // logits visible
                float s = 0.f;
                for (int idx = b + (lane >> 2); idx < bEnd; idx += 16) {
                    float x = alpha_s[(size_t)idx * 4 + head];
                    float ex = __expf(x - mh);
                    s += ex;
                    alpha_s[(size_t)idx * 4 + head] = ex;
                }
                #pragma unroll
                for (int m = 4; m < 64; m <<= 1) s += __shfl_xor(s, m, 64);
                float inv = 1.f / (s + 1e-16f);
                asm volatile("s_waitcnt vmcnt(0)" ::: "memory");
                for (int idx = b + (lane >> 2); idx < bEnd; idx += 16)
                    alpha_s[(size_t)idx * 4 + head] *= inv;
            }
            ++n;
            if (i + 1 < e1) {
                b = bEnd;
                bEnd = soff[n + 1];
                small = (bEnd - b) <= 16;
                sj = dsrc[n * 4 + hd];
                mx = -1e30f;
                myLg = -1e30f;
            }
        }
        // rotate
        eaAa = eaNa; eaAb = eaNb;
        dA = dB; fA = fB;
        dB = dC; fB = fC;
        diA = diB;
    }
}

// ----------------- aggregation + head-mean + bias + LayerNorm (+PReLU) -------
// Flat edge-parallel with sentinel-padded streams; packed int2 {src|flag, pos}
// stream; LN/bias params hoisted to loop-invariant registers; self-loop edges
// skip the 56-dot2 ee chain via a wave-uniform branch.
__global__ __launch_bounds__(256) void k_aggr(const int* __restrict__ nstart,
                                              const int* __restrict__ doff,
                                              const int2* __restrict__ sd_d,
                                              const unsigned* __restrict__ ea_d,
                                              const unsigned* __restrict__ eeWp, const float* __restrict__ ebl,
                                              const float* __restrict__ pa, const ushort_t* __restrict__ xw,
                                              const float* __restrict__ alpha_s,
                                              const float* __restrict__ gbias, const float* __restrict__ lng,
                                              const float* __restrict__ lnb, const float* __restrict__ pgnn,
                                              int last, ushort_t* __restrict__ hb_out, float* __restrict__ fout) {
    int t = threadIdx.x;
    float a = pa[0], pg = pgnn[0];
    int lane = t & 63;
    int w = blockIdx.x * 4 + (t >> 6);
    int hd = lane >> 4;
    int cm = (lane & 15) * 8;
    int c0 = lane * 8;
    uint4 wpa[7], wpb[7];
    #pragma unroll
    for (int kp = 0; kp < 7; ++kp) {
        wpa[kp] = *(const uint4*)&eeWp[kp * HE + c0];
        wpb[kp] = *(const uint4*)&eeWp[kp * HE + c0 + 4];
    }
    float eb[8], ebp[8];
    #pragma unroll
    for (int q = 0; q < 8; ++q) {
        eb[q] = ebl[c0 + q];
        ebp[q] = prelu_f(eb[q], a);
    }
    // loop-invariant LN/bias params (hoisted out of the node-finish)
    float gbv[8], gv[8], bbv[8];
    *(float4*)&gbv[0] = *(const float4*)&gbias[cm];
    *(float4*)&gbv[4] = *(const float4*)&gbias[cm + 4];
    *(float4*)&gv[0]  = *(const float4*)&lng[cm];
    *(float4*)&gv[4]  = *(const float4*)&lng[cm + 4];
    *(float4*)&bbv[0] = *(const float4*)&lnb[cm];
    *(float4*)&bbv[4] = *(const float4*)&lnb[cm + 4];

    int n0 = nstart[w], n1 = nstart[w + 1];
    if (n0 >= n1) return;
    int e0 = doff[n0];
    int e1 = doff[n1];

    // pipeline prologue (streams sentinel-padded to NT+4, no clamps)
    int2 rA = sd_d[e0], rB = sd_d[e0 + 1], rN = sd_d[e0 + 2];
    int sA = rA.x & IMSK, fA = rA.x >> 30, pA = rA.y;
    int sB = rB.x & IMSK, fB = rB.x >> 30, pB = rB.y;
    int sN = rN.x & IMSK, fN = rN.x >> 30, pN = rN.y;
    uint4 xwA = *(const uint4*)&xw[(size_t)sA * HE + c0];
    float alA = alpha_s[(size_t)pA * 4 + hd];
    uint4 xwB = *(const uint4*)&xw[(size_t)sB * HE + c0];
    float alB = alpha_s[(size_t)pB * 4 + hd];
    uint4 eaCa = *(const uint4*)&ea_d[(size_t)e0 * 8];
    uint4 eaCb = *(const uint4*)&ea_d[(size_t)e0 * 8 + 4];

    int n = n0;
    int b1 = doff[n0 + 1];
    int nn2 = (n0 + 2 <= NN) ? n0 + 2 : NN;
    int b2 = doff[nn2];
    float acc[8] = {0.f, 0.f, 0.f, 0.f, 0.f, 0.f, 0.f, 0.f};

    for (int i = e0; i < e1; ++i) {
        // (1) packed ea stream prefetch for i+1
        uint4 eaNa = *(const uint4*)&ea_d[(size_t)(i + 1) * 8];
        uint4 eaNb = *(const uint4*)&ea_d[(size_t)(i + 1) * 8 + 4];
        // (2) gathers for i+2 (indices loaded last iteration)
        uint4 xwC = *(const uint4*)&xw[(size_t)sN * HE + c0];
        float alC = alpha_s[(size_t)pN * 4 + hd];
        // (3) indices for i+3 (one 8B load)
        int2 rN2 = sd_d[i + 3];
        int sN2 = rN2.x & IMSK, fN2 = rN2.x >> 30, pN2 = rN2.y;
        // (4) compute current edge (slot A): ee via 56 dot2, skipped for self
        float pw[8];
        if (__builtin_amdgcn_readfirstlane(fA)) {
            #pragma unroll
            for (int q = 0; q < 8; ++q) pw[q] = ebp[q];
        } else {
            unsigned ec[7] = {eaCa.x, eaCa.y, eaCa.z, eaCa.w, eaCb.x, eaCb.y, eaCb.z};
            float wv[8];
            #pragma unroll
            for (int q = 0; q < 8; ++q) wv[q] = eb[q];
            #pragma unroll
            for (int kp = 0; kp < 7; ++kp) {
                wv[0] = dot2(ec[kp], wpa[kp].x, wv[0]);
                wv[1] = dot2(ec[kp], wpa[kp].y, wv[1]);
                wv[2] = dot2(ec[kp], wpa[kp].z, wv[2]);
                wv[3] = dot2(ec[kp], wpa[kp].w, wv[3]);
                wv[4] = dot2(ec[kp], wpb[kp].x, wv[4]);
                wv[5] = dot2(ec[kp], wpb[kp].y, wv[5]);
                wv[6] = dot2(ec[kp], wpb[kp].z, wv[6]);
                wv[7] = dot2(ec[kp], wpb[kp].w, wv[7]);
            }
            #pragma unroll
            for (int q = 0; q < 8; ++q) pw[q] = prelu_f(wv[q], a);
        }
        float xv[8] = {bflo(xwA.x), bfhi(xwA.x), bflo(xwA.y), bfhi(xwA.y),
                       bflo(xwA.z), bfhi(xwA.z), bflo(xwA.w), bfhi(xwA.w)};
        #pragma unroll
        for (int q = 0; q < 8; ++q) acc[q] += (xv[q] + pw[q]) * alA;
        // (5) node boundary: finish node n
        if (i + 1 == b1) {
            float hm[8];
            #pragma unroll
            for (int q = 0; q < 8; ++q) {
                float v = acc[q];
                v += __shfl_xor(v, 16, 64);
                v += __shfl_xor(v, 32, 64);
                hm[q] = 0.25f * v + gbv[q];
            }
            float s8 = 0.f, q8 = 0.f;
            #pragma unroll
            for (int q = 0; q < 8; ++q) { s8 += hm[q]; q8 += hm[q] * hm[q]; }
            #pragma unroll
            for (int m = 1; m < 16; m <<= 1) {
                s8 += __shfl_xor(s8, m, 64);
                q8 += __shfl_xor(q8, m, 64);
            }
            float mu = s8 * (1.f / 128.f);
            float var = q8 * (1.f / 128.f) - mu * mu;
            float rstd = rsqrtf(var + 1e-5f);
            if (lane < 16) {
                float o[8];
                #pragma unroll
                for (int q = 0; q < 8; ++q) {
                    float v = (hm[q] - mu) * rstd * gv[q] + bbv[q];
                    o[q] = last ? v : prelu_f(v, pg);
                }
                if (last) {
                    float4* op = (float4*)&fout[(size_t)n * EMB + lane * 8];
                    op[0] = make_float4(o[0], o[1], o[2], o[3]);
                    op[1] = make_float4(o[4], o[5], o[6], o[7]);
                } else {
                    uint4 ob;
                    ob.x = (unsigned)f2bf(o[0]) | ((unsigned)f2bf(o[1]) << 16);
                    ob.y = (unsigned)f2bf(o[2]) | ((unsigned)f2bf(o[3]) << 16);
                    ob.z = (unsigned)f2bf(o[4]) | ((unsigned)f2bf(o[5]) << 16);
                    ob.w = (unsigned)f2bf(o[6]) | ((unsigned)f2bf(o[7]) << 16);
                    *(uint4*)&hb_out[(size_t)n * EMB + lane * 8] = ob;
                }
            }
            #pragma unroll
            for (int q = 0; q < 8; ++q) acc[q] = 0.f;
            ++n;
            b1 = b2;
            int nx = (n + 2 <= NN) ? n + 2 : NN;
            b2 = doff[nx];
        }
        // (6) rotate pipeline
        xwA = xwB; alA = alB;
        xwB = xwC; alB = alC;
        sN = sN2; pN = pN2;
        fA = fB; fB = fN; fN = fN2;
        eaCa = eaNa; eaCb = eaNb;
    }
}

extern "C" void kernel_launch(void* const* d_in, const int* in_sizes, int n_in,
                              void* d_out, int out_size, void* d_ws, size_t ws_size,
                              hipStream_t stream) {
    const float* x     = (const float*)d_in[0];
    const int*   ei    = (const int*)d_in[1];      // int32 (JAX x64 disabled)
    const float* ea    = (const float*)d_in[2];
    const float* xembW = (const float*)d_in[3];
    const float* pgnn  = (const float*)d_in[4];
    const float* wlW   = (const float*)d_in[5];
    const float* wlb   = (const float*)d_in[6];
    const float* att   = (const float*)d_in[7];
    const float* gbias = (const float*)d_in[8];
    const float* eeW   = (const float*)d_in[9];
    const float* eeb   = (const float*)d_in[10];
    const float* pgat  = (const float*)d_in[11];
    const float* lng   = (const float*)d_in[12];
    const float* lnb   = (const float*)d_in[13];

    char* w = (char*)d_ws;
    size_t off = 0;
    auto alloc = [&](size_t nbytes) -> char* {
        char* p = w + off;
        off += (nbytes + 255) & ~(size_t)255;
        return p;
    };
    ushort_t* hb    = (ushort_t*)alloc((size_t)NN * EMB * 2);   // 25.6 MB bf16
    ushort_t* xw    = (ushort_t*)alloc((size_t)NN * HE * 2);    // 102.4 MB bf16
    ushort_t* Wtg   = (ushort_t*)alloc((size_t)4 * 512 * 128 * 2);
    ushort_t* Wxt   = (ushort_t*)alloc((size_t)128 * 128 * 2);  // 32 KB embed weights
    unsigned* eeWp  = (unsigned*)alloc((size_t)4 * 7 * 512 * 4);
    float*    ddst  = (float*)alloc((size_t)NN * 4 * 4);
    float*    dsrc  = (float*)alloc((size_t)NN * 4 * 4);
    float*    alpha = (float*)alloc((size_t)NT * 4 * 4);        // 8 MB (src-sorted)
    unsigned* ea_d  = (unsigned*)alloc((size_t)(NT + 4) * 8 * 4); // 16 MB packed dst-ordered
    unsigned* ea_s  = (unsigned*)alloc((size_t)(NT + 4) * 8 * 4); // 16 MB packed src-ordered
    int2* sd_d    = (int2*)alloc((size_t)(NT + 4) * 8);         // packed {src|flag, src-pos}
    int* cnt2     = (int*)alloc((size_t)2 * NN * 4);            // scnt+dcnt adjacent
    int* scnt     = cnt2;
    int* dcnt     = cnt2 + NN;
    int* soff     = (int*)alloc((size_t)(NN + 1) * 4);
    int* doff     = (int*)alloc((size_t)(NN + 1) * 4);
    int* scur     = (int*)alloc((size_t)NN * 4);
    int* dcur     = (int*)alloc((size_t)NN * 4);
    int* seid     = (int*)alloc((size_t)NT * 4);
    int* deid     = (int*)alloc((size_t)NT * 4);
    int* s2p      = (int*)alloc((size_t)NT * 4);                // eid -> src-sorted pos
    int* dst_s    = (int*)alloc((size_t)(NT + 4) * 4);          // src-ordered dst (+flag)
    int* nstart   = (int*)alloc((size_t)(NWAVE + 1) * 4);
    int* nstart_s = (int*)alloc((size_t)(NWAVE + 1) * 4);
    int* part     = (int*)alloc((size_t)2 * NN * 4);
    int* bsum     = (int*)alloc(512 * 4);

    // xb (bf16 padded x, 25.6 MB) aliases xw: dead before layer-0 k_gemm writes xw
    ushort_t* xb = xw;

    hipMemsetAsync(cnt2, 0, (size_t)2 * NN * 4, stream);
    k_count<<<(NT + 255) / 256, 256, 0, stream>>>(ei, scnt, dcnt);
    // joint scan over [scnt|dcnt] (2*NN = 200000 -> 391 blocks of 512)
    k_scan1<<<391, 512, 0, stream>>>(cnt2, part, bsum);
    k_scan2<<<1, 512, 0, stream>>>(bsum, 391);
    k_scan3<<<(2 * NN + 255) / 256, 256, 0, stream>>>(part, bsum, soff, scur, doff, dcur);
    k_fill<<<(NT + 255) / 256, 256, 0, stream>>>(ei, scur, dcur, seid, deid, s2p);
    k_wrange2<<<(NWAVE + 1 + 255) / 256, 256, 0, stream>>>(doff, soff, nstart, nstart_s);
    k_dprep<<<(NT + 4 + 255) / 256, 256, 0, stream>>>(deid, ei, ea, s2p, sd_d, ea_d);
    k_sprep<<<(NT + 4 + 255) / 256, 256, 0, stream>>>(seid, ei, ea, dst_s, ea_s);
    k_prep_all<<<(PREP_TOTAL + 255) / 256, 256, 0, stream>>>(x, xembW, wlW, eeW, xb, Wxt, Wtg, eeWp);
    k_embed_m<<<(NN + 63) / 64, 256, 0, stream>>>(xb, Wxt, pgnn, hb);

    for (int l = 0; l < 4; ++l) {
        const float* bl  = wlb + (size_t)l * HE;
        const float* al  = att + (size_t)l * 1024;
        const unsigned* eWl = eeWp + (size_t)l * 7 * HE;
        const float* ebl = eeb + (size_t)l * HE;
        const float* pa  = pgat + l;
        const ushort_t* Wt = Wtg + (size_t)l * 512 * 128;
        k_gemm<<<dim3((NN + 63) / 64, 4), 256, 0, stream>>>(hb, Wt, bl, pa, al, xw, ddst, dsrc);
        k_edgesm<<<2048, 256, 0, stream>>>(nstart_s, soff, ea_s, dst_s, eWl, ebl, al, pa,
                                           ddst, dsrc, alpha);
        k_aggr<<<2048, 256, 0, stream>>>(nstart, doff, sd_d, ea_d, eWl, ebl, pa, xw, alpha,
                                         gbias + (size_t)l * EMB, lng + (size_t)l * EMB,
                                         lnb + (size_t)l * EMB, pgnn, (l == 3) ? 1 : 0,
                                         hb, (float*)d_out);
    }
}